// Round 14
// baseline (144.307 us; speedup 1.0000x reference)
//
#include <hip/hip_runtime.h>
#include <hip/hip_bf16.h>
#include <stdint.h>

#define B_ 4
#define H_ 16
#define S_ 2048
#define D_ 64
#define QBLK 128
#define KBLK 64
#define NT (S_ / KBLK)
#define LDW 72   // fallback kernel only
#define LOG2E 1.44269504088896340736f

typedef __attribute__((ext_vector_type(8))) short short8;
typedef __attribute__((ext_vector_type(4))) float f32x4;
typedef __attribute__((ext_vector_type(16))) float f32x16;
typedef _Float16 f16x8 __attribute__((ext_vector_type(8)));
typedef _Float16 f16x4 __attribute__((ext_vector_type(4)));
typedef __fp16 fp16x2 __attribute__((ext_vector_type(2)));

__device__ __forceinline__ unsigned short f2bf(float f) {
  union { float f; unsigned int u; } x; x.f = f;
  unsigned int u = x.u;
  unsigned int r = (u + 0x7FFFu + ((u >> 16) & 1u)) >> 16;
  return (unsigned short)r;
}
__device__ __forceinline__ float bf2f(unsigned short h) {
  union { unsigned int u; float f; } y; y.u = ((unsigned int)h) << 16;
  return y.f;
}

__device__ __forceinline__ unsigned pkrtz(float a, float b) {
  union { fp16x2 h; unsigned u; } c;
  c.h = __builtin_amdgcn_cvt_pkrtz(a, b);
  return c.u;
}
__device__ __forceinline__ fp16x2 u2h(unsigned u) {
  union { unsigned u; fp16x2 h; } c; c.u = u; return c.h;
}

__device__ __forceinline__ float fast_exp2(float x) {
#if __has_builtin(__builtin_amdgcn_exp2f)
  return __builtin_amdgcn_exp2f(x);
#else
  return exp2f(x);
#endif
}

// a' = {a.row0, b.row0}, b' = {a.row1, b.row1}  (rows = 32-lane halves)
__device__ __forceinline__ void swap32(unsigned &a, unsigned &b) {
#if __has_builtin(__builtin_amdgcn_permlane32_swap)
  typedef int i32x2 __attribute__((ext_vector_type(2)));
  i32x2 r = __builtin_amdgcn_permlane32_swap((int)a, (int)b, false, false);
  a = (unsigned)r[0]; b = (unsigned)r[1];
#else
  asm("v_permlane32_swap_b32 %0, %1" : "+v"(a), "+v"(b));
#endif
}

__device__ __forceinline__ float pairmax(float x) {
  unsigned a = __float_as_uint(x), b = a;
  swap32(a, b);
  return fmaxf(__uint_as_float(a), __uint_as_float(b));
}
__device__ __forceinline__ float pairsum(float x) {
  unsigned a = __float_as_uint(x), b = a;
  swap32(a, b);
  return __uint_as_float(a) + __uint_as_float(b);
}

#define GLOAD16(g, l) __builtin_amdgcn_global_load_lds( \
    (const __attribute__((address_space(1))) unsigned int*)(g), \
    (__attribute__((address_space(3))) unsigned int*)(l), 16, 0, 0)

// ---------- prep 1: K fp32 -> swizzled fp16 plane ([S][128B] per bh) ----------
__global__ void prep_k(const float* __restrict__ K, _Float16* __restrict__ Kp) {
  int e4 = (blockIdx.x * 256 + threadIdx.x) * 4;
  int bh  = e4 >> 17;
  int rem = e4 & 131071;
  int s   = rem >> 6;
  int d0  = rem & 63;
  const float4 kv = *(const float4*)(K + (size_t)e4);
  f16x4 h;
  h[0] = (_Float16)kv.x; h[1] = (_Float16)kv.y;
  h[2] = (_Float16)kv.z; h[3] = (_Float16)kv.w;
  size_t off = ((size_t)bh * S_ + s) * 128 + (unsigned)((d0 * 2) ^ ((s & 7) << 4));
  *(f16x4*)((char*)Kp + off) = h;
}

// ---------- prep 2: V fp32 -> swizzled fp16 V^T plane ([64 d][S] per bh) ----------
__global__ void prep_v(const float* __restrict__ V, _Float16* __restrict__ Vt) {
  __shared__ _Float16 tile[64][66];
  int bh = blockIdx.x >> 5;
  int st = blockIdx.x & 31;
  const float* Vb = V + ((size_t)bh * S_ + st * 64) * 64;
  int tid = threadIdx.x;
  #pragma unroll
  for (int i = 0; i < 4; ++i) {
    int idx = i * 1024 + tid * 4;
    int r = idx >> 6, c = idx & 63;
    float4 vv = *(const float4*)(Vb + (size_t)r * 64 + c);
    f16x4 o;
    o[0] = (_Float16)vv.x; o[1] = (_Float16)vv.y;
    o[2] = (_Float16)vv.z; o[3] = (_Float16)vv.w;
    *(f16x4*)&tile[r][c] = o;
  }
  __syncthreads();
  int chunk = tid & 15;
  int dbase = tid >> 4;
  size_t outb = (size_t)bh * (64 * S_ * 2) + (size_t)st * 128;
  #pragma unroll
  for (int i = 0; i < 4; ++i) {
    int d = dbase + i * 16;
    f16x4 o;
    o[0] = tile[chunk * 4 + 0][d];
    o[1] = tile[chunk * 4 + 1][d];
    o[2] = tile[chunk * 4 + 2][d];
    o[3] = tile[chunk * 4 + 3][d];
    size_t off = outb + (size_t)d * (S_ * 2) + (unsigned)((chunk * 8) ^ ((d & 7) << 4));
    *(f16x4*)((char*)Vt + off) = o;
  }
}

// ---------- main: counted-vmcnt pipeline (T4), 3 LDS buffers, plain s_barrier ----------
__global__ __launch_bounds__(256)
void attn_fwd9(const float* __restrict__ Q, const _Float16* __restrict__ Kg,
               const _Float16* __restrict__ Vg, float* __restrict__ O) {
  __shared__ char smem[49152];   // 3 bufs x (K 8K | V 8K); epilogue reuses 32K

  const int tid  = threadIdx.x;
  const int lane = tid & 63;
  const int wid  = tid >> 6;
  const int l31  = lane & 31;
  const int hi   = lane >> 5;

  // grid: x = bh (64) -> XCD-local K/V (L2-resident); y = qtile (16)
  const int bh    = blockIdx.x;
  const int qtile = blockIdx.y;

  const char* KB = (const char*)Kg + (size_t)bh * (S_ * 128);
  const char* VB = (const char*)Vg + (size_t)bh * (64 * S_ * 2);
  const float* Qb = Q + (size_t)bh * S_ * D_;
  float*       Ob = O + (size_t)bh * S_ * D_;

  // ---- Q fragments (B-operand of swapped QK^T), pre-scaled by log2(e) ----
  const int qrow = qtile * QBLK + wid * 32 + l31;
  f16x8 qf[4];
  #pragma unroll
  for (int ds = 0; ds < 4; ++ds) {
    const float* qp = Qb + (size_t)qrow * D_ + ds * 16 + hi * 8;
    float4 a = *(const float4*)(qp);
    float4 b = *(const float4*)(qp + 4);
    qf[ds][0] = (_Float16)(a.x * LOG2E); qf[ds][1] = (_Float16)(a.y * LOG2E);
    qf[ds][2] = (_Float16)(a.z * LOG2E); qf[ds][3] = (_Float16)(a.w * LOG2E);
    qf[ds][4] = (_Float16)(b.x * LOG2E); qf[ds][5] = (_Float16)(b.y * LOG2E);
    qf[ds][6] = (_Float16)(b.z * LOG2E); qf[ds][7] = (_Float16)(b.w * LOG2E);
  }

  f32x16 oacc[2];
  #pragma unroll
  for (int dn = 0; dn < 2; ++dn)
    #pragma unroll
    for (int r = 0; r < 16; ++r) oacc[dn][r] = 0.f;
  float m_r = -INFINITY, l_r = 0.f;

  f32x16 zero16;
  #pragma unroll
  for (int r = 0; r < 16; ++r) zero16[r] = 0.f;

  // 4 global_load_lds per wave per STAGE
  #define STAGE(buf, kb)                                                        \
    {                                                                           \
      char* Kl_ = smem + (buf) * 16384;                                         \
      char* Vl_ = Kl_ + 8192;                                                   \
      _Pragma("unroll")                                                         \
      for (int c = 0; c < 4; ++c) {                                             \
        int id = c * 4 + wid;                                                   \
        if (id < 8) {                                                           \
          GLOAD16(KB + (size_t)(kb) * 128 + id * 1024 + lane * 16,              \
                  Kl_ + id * 1024);                                             \
        } else {                                                                \
          int i = id - 8;                                                       \
          GLOAD16(VB + (size_t)(i * 8 + (lane >> 3)) * (S_ * 2)                 \
                     + ((kb) >> 6) * 128 + (lane & 7) * 16,                     \
                  Vl_ + i * 1024);                                              \
        }                                                                       \
      }                                                                         \
    }

  // prologue: tiles 0 and 1 in flight (8 loads outstanding per wave)
  STAGE(0, 0);
  STAGE(1, KBLK);

  for (int it = 0; it < NT; ++it) {
    // wait for OWN oldest loads (this tile's); keep next tile's 4 in flight.
    // then plain barrier: every wave waited its own -> buffer complete for all.
    if (it == NT - 1) {
      asm volatile("s_waitcnt vmcnt(0)" ::: "memory");
    } else {
      asm volatile("s_waitcnt vmcnt(4)" ::: "memory");
    }
    __builtin_amdgcn_s_barrier();
    __builtin_amdgcn_sched_barrier(0);

    if (it + 2 < NT) STAGE((it + 2) % 3, (it + 2) * KBLK);

    const char* Kl = smem + (it % 3) * 16384;
    const char* Vl = Kl + 8192;

    // ---- QK^T both halves (log2 domain) ----
    f32x16 sacc_a, sacc_b;
    __builtin_amdgcn_s_setprio(1);
    {
      const int row = l31;
      const int sw = (row & 7) << 4;
      sacc_a = __builtin_amdgcn_mfma_f32_32x32x16_f16(
          *(const f16x8*)(Kl + row * 128 + ((0 * 32 + hi * 16) ^ sw)), qf[0], zero16, 0, 0, 0);
      #pragma unroll
      for (int ds = 1; ds < 4; ++ds)
        sacc_a = __builtin_amdgcn_mfma_f32_32x32x16_f16(
            *(const f16x8*)(Kl + row * 128 + ((ds * 32 + hi * 16) ^ sw)), qf[ds], sacc_a, 0, 0, 0);
    }
    {
      const int row = 32 + l31;
      const int sw = (row & 7) << 4;
      sacc_b = __builtin_amdgcn_mfma_f32_32x32x16_f16(
          *(const f16x8*)(Kl + row * 128 + ((0 * 32 + hi * 16) ^ sw)), qf[0], zero16, 0, 0, 0);
      #pragma unroll
      for (int ds = 1; ds < 4; ++ds)
        sacc_b = __builtin_amdgcn_mfma_f32_32x32x16_f16(
            *(const f16x8*)(Kl + row * 128 + ((ds * 32 + hi * 16) ^ sw)), qf[ds], sacc_b, 0, 0, 0);
    }
    __builtin_amdgcn_s_setprio(0);

    // ================= half A: keys [0,32) =================
    {
      float v0 = fmaxf(fmaxf(sacc_a[0], sacc_a[1]), sacc_a[2]);
      float v1 = fmaxf(fmaxf(sacc_a[3], sacc_a[4]), sacc_a[5]);
      float v2 = fmaxf(fmaxf(sacc_a[6], sacc_a[7]), sacc_a[8]);
      float v3 = fmaxf(fmaxf(sacc_a[9], sacc_a[10]), sacc_a[11]);
      float v4 = fmaxf(fmaxf(sacc_a[12], sacc_a[13]), sacc_a[14]);
      float w0 = fmaxf(fmaxf(v0, v1), v2);
      float w1 = fmaxf(fmaxf(v3, v4), sacc_a[15]);
      float mx = pairmax(fmaxf(w0, w1));
      if (!__all(mx <= m_r + 8.f)) {
        float nm = fmaxf(m_r, mx);
        float sc = fast_exp2(m_r - nm);
        m_r = nm; l_r *= sc;
        #pragma unroll
        for (int dn = 0; dn < 2; ++dn)
          #pragma unroll
          for (int r = 0; r < 16; ++r) oacc[dn][r] *= sc;
      }
      unsigned ww[8];
      #pragma unroll
      for (int r1 = 0; r1 < 4; ++r1) {
        float p0 = fast_exp2(sacc_a[4 * r1 + 0] - m_r);
        float p1 = fast_exp2(sacc_a[4 * r1 + 1] - m_r);
        float p2 = fast_exp2(sacc_a[4 * r1 + 2] - m_r);
        float p3 = fast_exp2(sacc_a[4 * r1 + 3] - m_r);
        ww[r1 * 2 + 0] = pkrtz(p0, p1);
        ww[r1 * 2 + 1] = pkrtz(p2, p3);
      }
      {
        const fp16x2 ones = {(__fp16)1.f, (__fp16)1.f};
        float rA = __builtin_amdgcn_fdot2(u2h(ww[0]), ones, 0.f, false);
        float rB = __builtin_amdgcn_fdot2(u2h(ww[1]), ones, 0.f, false);
        rA = __builtin_amdgcn_fdot2(u2h(ww[2]), ones, rA, false);
        rB = __builtin_amdgcn_fdot2(u2h(ww[3]), ones, rB, false);
        rA = __builtin_amdgcn_fdot2(u2h(ww[4]), ones, rA, false);
        rB = __builtin_amdgcn_fdot2(u2h(ww[5]), ones, rB, false);
        rA = __builtin_amdgcn_fdot2(u2h(ww[6]), ones, rA, false);
        rB = __builtin_amdgcn_fdot2(u2h(ww[7]), ones, rB, false);
        l_r += rA + rB;
      }
      f16x8 pb0, pb1;
      {
        unsigned u0 = ww[0], u1 = ww[1], u2 = ww[2], u3 = ww[3];
        swap32(u0, u2); swap32(u1, u3);
        union { unsigned u[4]; f16x8 v; } c;
        c.u[0] = u0; c.u[1] = u1; c.u[2] = u2; c.u[3] = u3;
        pb0 = c.v;
      }
      {
        unsigned u0 = ww[4], u1 = ww[5], u2 = ww[6], u3 = ww[7];
        swap32(u0, u2); swap32(u1, u3);
        union { unsigned u[4]; f16x8 v; } c;
        c.u[0] = u0; c.u[1] = u1; c.u[2] = u2; c.u[3] = u3;
        pb1 = c.v;
      }
      __builtin_amdgcn_s_setprio(1);
      #pragma unroll
      for (int dn = 0; dn < 2; ++dn) {
        const int d = dn * 32 + l31;
        const int sw = (d & 7) << 4;
        f16x8 vf0 = *(const f16x8*)(Vl + d * 128 + ((0 * 32 + hi * 16) ^ sw));
        f16x8 vf1 = *(const f16x8*)(Vl + d * 128 + ((1 * 32 + hi * 16) ^ sw));
        oacc[dn] = __builtin_amdgcn_mfma_f32_32x32x16_f16(vf0, pb0, oacc[dn], 0, 0, 0);
        oacc[dn] = __builtin_amdgcn_mfma_f32_32x32x16_f16(vf1, pb1, oacc[dn], 0, 0, 0);
      }
      __builtin_amdgcn_s_setprio(0);
    }

    // ================= half B: keys [32,64) =================
    {
      float v0 = fmaxf(fmaxf(sacc_b[0], sacc_b[1]), sacc_b[2]);
      float v1 = fmaxf(fmaxf(sacc_b[3], sacc_b[4]), sacc_b[5]);
      float v2 = fmaxf(fmaxf(sacc_b[6], sacc_b[7]), sacc_b[8]);
      float v3 = fmaxf(fmaxf(sacc_b[9], sacc_b[10]), sacc_b[11]);
      float v4 = fmaxf(fmaxf(sacc_b[12], sacc_b[13]), sacc_b[14]);
      float w0 = fmaxf(fmaxf(v0, v1), v2);
      float w1 = fmaxf(fmaxf(v3, v4), sacc_b[15]);
      float mx = pairmax(fmaxf(w0, w1));
      if (!__all(mx <= m_r + 8.f)) {
        float nm = fmaxf(m_r, mx);
        float sc = fast_exp2(m_r - nm);
        m_r = nm; l_r *= sc;
        #pragma unroll
        for (int dn = 0; dn < 2; ++dn)
          #pragma unroll
          for (int r = 0; r < 16; ++r) oacc[dn][r] *= sc;
      }
      unsigned ww[8];
      #pragma unroll
      for (int r1 = 0; r1 < 4; ++r1) {
        float p0 = fast_exp2(sacc_b[4 * r1 + 0] - m_r);
        float p1 = fast_exp2(sacc_b[4 * r1 + 1] - m_r);
        float p2 = fast_exp2(sacc_b[4 * r1 + 2] - m_r);
        float p3 = fast_exp2(sacc_b[4 * r1 + 3] - m_r);
        ww[r1 * 2 + 0] = pkrtz(p0, p1);
        ww[r1 * 2 + 1] = pkrtz(p2, p3);
      }
      {
        const fp16x2 ones = {(__fp16)1.f, (__fp16)1.f};
        float rA = __builtin_amdgcn_fdot2(u2h(ww[0]), ones, 0.f, false);
        float rB = __builtin_amdgcn_fdot2(u2h(ww[1]), ones, 0.f, false);
        rA = __builtin_amdgcn_fdot2(u2h(ww[2]), ones, rA, false);
        rB = __builtin_amdgcn_fdot2(u2h(ww[3]), ones, rB, false);
        rA = __builtin_amdgcn_fdot2(u2h(ww[4]), ones, rA, false);
        rB = __builtin_amdgcn_fdot2(u2h(ww[5]), ones, rB, false);
        rA = __builtin_amdgcn_fdot2(u2h(ww[6]), ones, rA, false);
        rB = __builtin_amdgcn_fdot2(u2h(ww[7]), ones, rB, false);
        l_r += rA + rB;
      }
      f16x8 pb2, pb3;
      {
        unsigned u0 = ww[0], u1 = ww[1], u2 = ww[2], u3 = ww[3];
        swap32(u0, u2); swap32(u1, u3);
        union { unsigned u[4]; f16x8 v; } c;
        c.u[0] = u0; c.u[1] = u1; c.u[2] = u2; c.u[3] = u3;
        pb2 = c.v;
      }
      {
        unsigned u0 = ww[4], u1 = ww[5], u2 = ww[6], u3 = ww[7];
        swap32(u0, u2); swap32(u1, u3);
        union { unsigned u[4]; f16x8 v; } c;
        c.u[0] = u0; c.u[1] = u1; c.u[2] = u2; c.u[3] = u3;
        pb3 = c.v;
      }
      __builtin_amdgcn_s_setprio(1);
      #pragma unroll
      for (int dn = 0; dn < 2; ++dn) {
        const int d = dn * 32 + l31;
        const int sw = (d & 7) << 4;
        f16x8 vf2 = *(const f16x8*)(Vl + d * 128 + ((2 * 32 + hi * 16) ^ sw));
        f16x8 vf3 = *(const f16x8*)(Vl + d * 128 + ((3 * 32 + hi * 16) ^ sw));
        oacc[dn] = __builtin_amdgcn_mfma_f32_32x32x16_f16(vf2, pb2, oacc[dn], 0, 0, 0);
        oacc[dn] = __builtin_amdgcn_mfma_f32_32x32x16_f16(vf3, pb3, oacc[dn], 0, 0, 0);
      }
      __builtin_amdgcn_s_setprio(0);
    }
    // no trailing barrier: next iteration's waitcnt+barrier handles it
  }
  #undef STAGE

  __syncthreads();   // all waves done with K/V bufs before reusing smem

  // ---- epilogue: O^T -> LDS (per-wave 8KB) -> coalesced O stores ----
  const float inv = 1.0f / pairsum(l_r);
  float* Ep = (float*)(smem + wid * 8192);   // [64 d][32 q]
  #pragma unroll
  for (int dn = 0; dn < 2; ++dn)
    #pragma unroll
    for (int r = 0; r < 16; ++r) {
      int d = dn * 32 + (r & 3) + 8 * (r >> 2) + 4 * hi;
      Ep[d * 32 + l31] = oacc[dn][r] * inv;
    }
  __syncthreads();
  const int q2 = lane >> 1, dh = lane & 1;
  float* orow = Ob + (size_t)(qtile * QBLK + wid * 32 + q2) * D_ + dh * 32;
  #pragma unroll
  for (int c = 0; c < 8; ++c) {
    float4 o4;
    o4.x = Ep[(dh * 32 + c * 4 + 0) * 32 + q2];
    o4.y = Ep[(dh * 32 + c * 4 + 1) * 32 + q2];
    o4.z = Ep[(dh * 32 + c * 4 + 2) * 32 + q2];
    o4.w = Ep[(dh * 32 + c * 4 + 3) * 32 + q2];
    *(float4*)(orow + c * 4) = o4;
  }
}

// ---------- fallback (round-3 double-bf16 kernel, used only if ws too small) ----------
__global__ __launch_bounds__(256, 2)
void attn_fwd(const float* __restrict__ Q, const float* __restrict__ K,
              const float* __restrict__ V, float* __restrict__ O) {
  __shared__ alignas(16) unsigned short Kh_lds[KBLK * LDW];
  __shared__ alignas(16) unsigned short Kl_lds[KBLK * LDW];
  __shared__ alignas(16) unsigned short Vt_lds[D_ * LDW];
  __shared__ alignas(16) unsigned short P_lds[4][16 * LDW];

  const int tid  = threadIdx.x;
  const int lane = tid & 63;
  const int wid  = tid >> 6;
  const int l15  = lane & 15;
  const int dgrp = lane >> 4;

  const int qtile = blockIdx.x;
  const int bh    = blockIdx.y;

  const size_t base = (size_t)bh * S_ * D_;
  const float* Qb = Q + base;
  const float* Kb = K + base;
  const float* Vb = V + base;
  float*       Ob = O + base;

  const int qrow = qtile * 64 + wid * 16 + l15;
  short8 qfh[2], qfl[2];
  {
    const float* qp = Qb + (size_t)qrow * D_ + dgrp * 8;
    #pragma unroll
    for (int s = 0; s < 2; ++s)
      #pragma unroll
      for (int j = 0; j < 8; ++j) {
        float f = qp[s * 32 + j];
        unsigned short h = f2bf(f);
        qfh[s][j] = (short)h;
        qfl[s][j] = (short)f2bf(f - bf2f(h));
      }
  }

  f32x4 oacc[4];
  #pragma unroll
  for (int t = 0; t < 4; ++t) oacc[t] = f32x4{0.f, 0.f, 0.f, 0.f};
  float m_r[4], l_r[4];
  #pragma unroll
  for (int j = 0; j < 4; ++j) { m_r[j] = -INFINITY; l_r[j] = 0.f; }

  for (int kb = 0; kb < S_; kb += KBLK) {
    __syncthreads();
    #pragma unroll
    for (int c = 0; c < 4; ++c) {
      int e = (c * 256 + tid) * 4;
      int r = e >> 6, col = e & 63;
      const float4 kv = *(const float4*)(Kb + (size_t)(kb + r) * D_ + col);
      ushort4 kh, kl;
      kh.x = f2bf(kv.x); kl.x = f2bf(kv.x - bf2f(kh.x));
      kh.y = f2bf(kv.y); kl.y = f2bf(kv.y - bf2f(kh.y));
      kh.z = f2bf(kv.z); kl.z = f2bf(kv.z - bf2f(kh.z));
      kh.w = f2bf(kv.w); kl.w = f2bf(kv.w - bf2f(kh.w));
      *(ushort4*)&Kh_lds[r * LDW + col] = kh;
      *(ushort4*)&Kl_lds[r * LDW + col] = kl;
      const float4 vv = *(const float4*)(Vb + (size_t)(kb + r) * D_ + col);
      Vt_lds[(col + 0) * LDW + r] = f2bf(vv.x);
      Vt_lds[(col + 1) * LDW + r] = f2bf(vv.y);
      Vt_lds[(col + 2) * LDW + r] = f2bf(vv.z);
      Vt_lds[(col + 3) * LDW + r] = f2bf(vv.w);
    }
    __syncthreads();

    f32x4 sa[4];
    #pragma unroll
    for (int t = 0; t < 4; ++t) {
      sa[t] = f32x4{0.f, 0.f, 0.f, 0.f};
      #pragma unroll
      for (int s = 0; s < 2; ++s) {
        const int off = (t * 16 + l15) * LDW + s * 32 + dgrp * 8;
        short8 kfh = *(const short8*)&Kh_lds[off];
        short8 kfl = *(const short8*)&Kl_lds[off];
        sa[t] = __builtin_amdgcn_mfma_f32_16x16x32_bf16(qfh[s], kfh, sa[t], 0, 0, 0);
        sa[t] = __builtin_amdgcn_mfma_f32_16x16x32_bf16(qfh[s], kfl, sa[t], 0, 0, 0);
        sa[t] = __builtin_amdgcn_mfma_f32_16x16x32_bf16(qfl[s], kfh, sa[t], 0, 0, 0);
      }
    }

    float pmax[4];
    #pragma unroll
    for (int j = 0; j < 4; ++j) {
      float mx = fmaxf(fmaxf(sa[0][j], sa[1][j]), fmaxf(sa[2][j], sa[3][j]));
      #pragma unroll
      for (int m = 1; m < 16; m <<= 1) mx = fmaxf(mx, __shfl_xor(mx, m));
      pmax[j] = mx;
    }
    float scale[4];
    #pragma unroll
    for (int j = 0; j < 4; ++j) {
      float nm = fmaxf(m_r[j], pmax[j]);
      scale[j] = __expf(m_r[j] - nm);
      m_r[j] = nm;
    }
    float rs[4] = {0.f, 0.f, 0.f, 0.f};
    #pragma unroll
    for (int t = 0; t < 4; ++t)
      #pragma unroll
      for (int j = 0; j < 4; ++j) {
        float p = __expf(sa[t][j] - m_r[j]);
        rs[j] += p;
        P_lds[wid][(dgrp * 4 + j) * LDW + t * 16 + l15] = f2bf(p);
      }
    #pragma unroll
    for (int j = 0; j < 4; ++j) {
      #pragma unroll
      for (int m = 1; m < 16; m <<= 1) rs[j] += __shfl_xor(rs[j], m);
      l_r[j] = l_r[j] * scale[j] + rs[j];
      #pragma unroll
      for (int t = 0; t < 4; ++t) oacc[t][j] *= scale[j];
    }

    #pragma unroll
    for (int s = 0; s < 2; ++s) {
      short8 pf = *(const short8*)&P_lds[wid][l15 * LDW + s * 32 + dgrp * 8];
      #pragma unroll
      for (int t = 0; t < 4; ++t) {
        short8 vf = *(const short8*)&Vt_lds[(t * 16 + l15) * LDW + s * 32 + dgrp * 8];
        oacc[t] = __builtin_amdgcn_mfma_f32_16x16x32_bf16(pf, vf, oacc[t], 0, 0, 0);
      }
    }
  }

  #pragma unroll
  for (int j = 0; j < 4; ++j) {
    float inv = 1.0f / l_r[j];
    int row = qtile * 64 + wid * 16 + dgrp * 4 + j;
    float* op = Ob + (size_t)row * D_ + l15;
    #pragma unroll
    for (int t = 0; t < 4; ++t)
      op[t * 16] = oacc[t][j] * inv;
  }
}

extern "C" void kernel_launch(void* const* d_in, const int* in_sizes, int n_in,
                              void* d_out, int out_size, void* d_ws, size_t ws_size,
                              hipStream_t stream) {
  const float* q = (const float*)d_in[0];
  const float* k = (const float*)d_in[1];
  const float* v = (const float*)d_in[2];
  float* o = (float*)d_out;
  const size_t PLANE = (size_t)B_ * H_ * S_ * 128;   // 16 MiB per fp16 plane
  if (ws_size >= 2 * PLANE) {
    _Float16* Kp = (_Float16*)d_ws;
    _Float16* Vt = (_Float16*)((char*)d_ws + PLANE);
    prep_k<<<8192, 256, 0, stream>>>(k, Kp);
    prep_v<<<2048, 256, 0, stream>>>(v, Vt);
    attn_fwd9<<<dim3(B_ * H_, S_ / QBLK), 256, 0, stream>>>(q, Kp, Vt, o);
  } else {
    attn_fwd<<<dim3(S_ / 64, B_ * H_), 256, 0, stream>>>(q, k, v, o);
  }
}

// Round 15
// 142.137 us; speedup vs baseline: 1.0153x; 1.0153x over previous
//
#include <hip/hip_runtime.h>
#include <hip/hip_bf16.h>
#include <stdint.h>

#define B_ 4
#define H_ 16
#define S_ 2048
#define D_ 64
#define QBLK 128
#define KBLK 64
#define NT (S_ / KBLK)
#define LDW 72   // fallback kernel only
#define LOG2E 1.44269504088896340736f

typedef __attribute__((ext_vector_type(8))) short short8;
typedef __attribute__((ext_vector_type(4))) float f32x4;
typedef __attribute__((ext_vector_type(16))) float f32x16;
typedef _Float16 f16x8 __attribute__((ext_vector_type(8)));
typedef _Float16 f16x4 __attribute__((ext_vector_type(4)));
typedef __fp16 fp16x2 __attribute__((ext_vector_type(2)));

__device__ __forceinline__ unsigned short f2bf(float f) {
  union { float f; unsigned int u; } x; x.f = f;
  unsigned int u = x.u;
  unsigned int r = (u + 0x7FFFu + ((u >> 16) & 1u)) >> 16;
  return (unsigned short)r;
}
__device__ __forceinline__ float bf2f(unsigned short h) {
  union { unsigned int u; float f; } y; y.u = ((unsigned int)h) << 16;
  return y.f;
}

__device__ __forceinline__ unsigned pkrtz(float a, float b) {
  union { fp16x2 h; unsigned u; } c;
  c.h = __builtin_amdgcn_cvt_pkrtz(a, b);
  return c.u;
}
__device__ __forceinline__ fp16x2 u2h(unsigned u) {
  union { unsigned u; fp16x2 h; } c; c.u = u; return c.h;
}

__device__ __forceinline__ float fast_exp2(float x) {
#if __has_builtin(__builtin_amdgcn_exp2f)
  return __builtin_amdgcn_exp2f(x);
#else
  return exp2f(x);
#endif
}

// a' = {a.row0, b.row0}, b' = {a.row1, b.row1}  (rows = 32-lane halves)
__device__ __forceinline__ void swap32(unsigned &a, unsigned &b) {
#if __has_builtin(__builtin_amdgcn_permlane32_swap)
  typedef int i32x2 __attribute__((ext_vector_type(2)));
  i32x2 r = __builtin_amdgcn_permlane32_swap((int)a, (int)b, false, false);
  a = (unsigned)r[0]; b = (unsigned)r[1];
#else
  asm("v_permlane32_swap_b32 %0, %1" : "+v"(a), "+v"(b));
#endif
}

__device__ __forceinline__ float pairmax(float x) {
  unsigned a = __float_as_uint(x), b = a;
  swap32(a, b);
  return fmaxf(__uint_as_float(a), __uint_as_float(b));
}
__device__ __forceinline__ float pairsum(float x) {
  unsigned a = __float_as_uint(x), b = a;
  swap32(a, b);
  return __uint_as_float(a) + __uint_as_float(b);
}

// ---------- prep 1: K fp32 -> fragment-major fp16 plane ----------
// layout: [bh][tile(32)][frag f=b*4+ds (8)][lane (64)] x 16B  => 1KB per (tile,frag)
__global__ void prep_k(const float* __restrict__ K, _Float16* __restrict__ Kp) {
  int e4 = (blockIdx.x * 256 + threadIdx.x) * 4;
  int bh  = e4 >> 17;
  int rem = e4 & 131071;
  int s   = rem >> 6;
  int d0  = rem & 63;
  const float4 kv = *(const float4*)(K + (size_t)e4);
  f16x4 h;
  h[0] = (_Float16)kv.x; h[1] = (_Float16)kv.y;
  h[2] = (_Float16)kv.z; h[3] = (_Float16)kv.w;
  int tile = s >> 6, r = s & 63;
  int b = r >> 5, l31 = r & 31;
  int ds = d0 >> 4, hi = (d0 >> 3) & 1, j = d0 & 7;
  size_t off = (((size_t)bh * 32 + tile) * 8 + (b * 4 + ds)) * 1024
             + (hi * 32 + l31) * 16 + j * 2;
  *(f16x4*)((char*)Kp + off) = h;
}

// ---------- prep 2: V fp32 -> fragment-major fp16 V^T plane ----------
// layout: [bh][tile(32)][frag g=dn*4+ks (8)][lane (64)] x 16B
__global__ void prep_v(const float* __restrict__ V, _Float16* __restrict__ Vt) {
  __shared__ _Float16 tile[64][66];
  int bh = blockIdx.x >> 5;
  int st = blockIdx.x & 31;
  const float* Vb = V + ((size_t)bh * S_ + st * 64) * 64;
  int tid = threadIdx.x;
  #pragma unroll
  for (int i = 0; i < 4; ++i) {
    int idx = i * 1024 + tid * 4;
    int r = idx >> 6, c = idx & 63;
    float4 vv = *(const float4*)(Vb + (size_t)r * 64 + c);
    f16x4 o;
    o[0] = (_Float16)vv.x; o[1] = (_Float16)vv.y;
    o[2] = (_Float16)vv.z; o[3] = (_Float16)vv.w;
    *(f16x4*)&tile[r][c] = o;
  }
  __syncthreads();
  int chunk = tid & 15;        // s-chunk of 4 within tile
  int dbase = tid >> 4;        // 0..15
  int sbase = chunk * 4;
  int ks = sbase >> 4, hi = (sbase >> 3) & 1, j0 = sbase & 7;
  #pragma unroll
  for (int i = 0; i < 4; ++i) {
    int d = dbase + i * 16;
    f16x4 o;
    o[0] = tile[sbase + 0][d];
    o[1] = tile[sbase + 1][d];
    o[2] = tile[sbase + 2][d];
    o[3] = tile[sbase + 3][d];
    int dn = d >> 5, l31 = d & 31;
    size_t off = (((size_t)bh * 32 + st) * 8 + (dn * 4 + ks)) * 1024
               + (hi * 32 + l31) * 16 + j0 * 2;
    *(f16x4*)((char*)Vt + off) = o;
  }
}

// ---------- main: NO LDS / NO barriers in loop — K/V fragments straight L2->VGPR ----------
__global__ __launch_bounds__(256)
void attn_fwd10(const float* __restrict__ Q, const _Float16* __restrict__ Kg,
                const _Float16* __restrict__ Vg, float* __restrict__ O) {
  __shared__ char smem[32768];   // epilogue transpose scratch only

  const int tid  = threadIdx.x;
  const int lane = tid & 63;
  const int wid  = tid >> 6;
  const int l31  = lane & 31;
  const int hi   = lane >> 5;
  const int loff = lane * 16;

  // grid: x = bh (64) -> XCD-local K/V (L2-resident); y = qtile (16)
  const int bh    = blockIdx.x;
  const int qtile = blockIdx.y;

  const char* KB = (const char*)Kg + (size_t)bh * (32 * 8192);
  const char* VB = (const char*)Vg + (size_t)bh * (32 * 8192);
  const float* Qb = Q + (size_t)bh * S_ * D_;
  float*       Ob = O + (size_t)bh * S_ * D_;

  // ---- Q fragments (B-operand of swapped QK^T), pre-scaled by log2(e) ----
  const int qrow = qtile * QBLK + wid * 32 + l31;
  f16x8 qf[4];
  #pragma unroll
  for (int ds = 0; ds < 4; ++ds) {
    const float* qp = Qb + (size_t)qrow * D_ + ds * 16 + hi * 8;
    float4 a = *(const float4*)(qp);
    float4 b = *(const float4*)(qp + 4);
    qf[ds][0] = (_Float16)(a.x * LOG2E); qf[ds][1] = (_Float16)(a.y * LOG2E);
    qf[ds][2] = (_Float16)(a.z * LOG2E); qf[ds][3] = (_Float16)(a.w * LOG2E);
    qf[ds][4] = (_Float16)(b.x * LOG2E); qf[ds][5] = (_Float16)(b.y * LOG2E);
    qf[ds][6] = (_Float16)(b.z * LOG2E); qf[ds][7] = (_Float16)(b.w * LOG2E);
  }

  f32x16 oacc[2];
  #pragma unroll
  for (int dn = 0; dn < 2; ++dn)
    #pragma unroll
    for (int r = 0; r < 16; ++r) oacc[dn][r] = 0.f;
  float m_r = -INFINITY, l_r = 0.f;

  f32x16 zero16;
  #pragma unroll
  for (int r = 0; r < 16; ++r) zero16[r] = 0.f;

  // K double-buffer in registers; V loaded per tile. All loads are
  // wave-coalesced 1KB (base + lane*16) from the fragment-major planes.
  f16x8 kbufA[8], kbufB[8];
  #pragma unroll
  for (int f = 0; f < 8; ++f)
    kbufA[f] = *(const f16x8*)(KB + f * 1024 + loff);

  #define TILE_BODY(KC, KN, IT)                                                 \
  {                                                                             \
    const size_t tb = (size_t)(IT) * 8192;                                      \
    /* V for this tile: issue early, consumed at PV */                          \
    f16x8 vf[8];                                                                \
    _Pragma("unroll")                                                           \
    for (int g = 0; g < 8; ++g)                                                 \
      vf[g] = *(const f16x8*)(VB + tb + g * 1024 + loff);                       \
    /* QK^T both halves (log2 domain) */                                        \
    f32x16 sacc_a, sacc_b;                                                      \
    __builtin_amdgcn_s_setprio(1);                                              \
    sacc_a = __builtin_amdgcn_mfma_f32_32x32x16_f16(KC[0], qf[0], zero16, 0, 0, 0); \
    sacc_a = __builtin_amdgcn_mfma_f32_32x32x16_f16(KC[1], qf[1], sacc_a, 0, 0, 0); \
    sacc_a = __builtin_amdgcn_mfma_f32_32x32x16_f16(KC[2], qf[2], sacc_a, 0, 0, 0); \
    sacc_a = __builtin_amdgcn_mfma_f32_32x32x16_f16(KC[3], qf[3], sacc_a, 0, 0, 0); \
    sacc_b = __builtin_amdgcn_mfma_f32_32x32x16_f16(KC[4], qf[0], zero16, 0, 0, 0); \
    sacc_b = __builtin_amdgcn_mfma_f32_32x32x16_f16(KC[5], qf[1], sacc_b, 0, 0, 0); \
    sacc_b = __builtin_amdgcn_mfma_f32_32x32x16_f16(KC[6], qf[2], sacc_b, 0, 0, 0); \
    sacc_b = __builtin_amdgcn_mfma_f32_32x32x16_f16(KC[7], qf[3], sacc_b, 0, 0, 0); \
    __builtin_amdgcn_s_setprio(0);                                              \
    /* prefetch next tile's K into the other buffer */                          \
    if ((IT) + 1 < NT) {                                                        \
      _Pragma("unroll")                                                         \
      for (int f = 0; f < 8; ++f)                                               \
        KN[f] = *(const f16x8*)(KB + tb + 8192 + f * 1024 + loff);              \
    }                                                                           \
    /* ===== half A: keys [0,32) ===== */                                       \
    {                                                                           \
      float v0 = fmaxf(fmaxf(sacc_a[0], sacc_a[1]), sacc_a[2]);                 \
      float v1 = fmaxf(fmaxf(sacc_a[3], sacc_a[4]), sacc_a[5]);                 \
      float v2 = fmaxf(fmaxf(sacc_a[6], sacc_a[7]), sacc_a[8]);                 \
      float v3 = fmaxf(fmaxf(sacc_a[9], sacc_a[10]), sacc_a[11]);               \
      float v4 = fmaxf(fmaxf(sacc_a[12], sacc_a[13]), sacc_a[14]);              \
      float w0 = fmaxf(fmaxf(v0, v1), v2);                                      \
      float w1 = fmaxf(fmaxf(v3, v4), sacc_a[15]);                              \
      float mx = pairmax(fmaxf(w0, w1));                                        \
      if (!__all(mx <= m_r + 8.f)) {                                            \
        float nm = fmaxf(m_r, mx);                                              \
        float sc = fast_exp2(m_r - nm);                                         \
        m_r = nm; l_r *= sc;                                                    \
        _Pragma("unroll")                                                       \
        for (int dn = 0; dn < 2; ++dn)                                          \
          _Pragma("unroll")                                                     \
          for (int r = 0; r < 16; ++r) oacc[dn][r] *= sc;                       \
      }                                                                         \
      unsigned ww[8];                                                           \
      _Pragma("unroll")                                                         \
      for (int r1 = 0; r1 < 4; ++r1) {                                          \
        float p0 = fast_exp2(sacc_a[4 * r1 + 0] - m_r);                         \
        float p1 = fast_exp2(sacc_a[4 * r1 + 1] - m_r);                         \
        float p2 = fast_exp2(sacc_a[4 * r1 + 2] - m_r);                         \
        float p3 = fast_exp2(sacc_a[4 * r1 + 3] - m_r);                         \
        ww[r1 * 2 + 0] = pkrtz(p0, p1);                                         \
        ww[r1 * 2 + 1] = pkrtz(p2, p3);                                         \
      }                                                                         \
      {                                                                         \
        const fp16x2 ones = {(__fp16)1.f, (__fp16)1.f};                         \
        float rA = __builtin_amdgcn_fdot2(u2h(ww[0]), ones, 0.f, false);        \
        float rB = __builtin_amdgcn_fdot2(u2h(ww[1]), ones, 0.f, false);        \
        rA = __builtin_amdgcn_fdot2(u2h(ww[2]), ones, rA, false);               \
        rB = __builtin_amdgcn_fdot2(u2h(ww[3]), ones, rB, false);               \
        rA = __builtin_amdgcn_fdot2(u2h(ww[4]), ones, rA, false);               \
        rB = __builtin_amdgcn_fdot2(u2h(ww[5]), ones, rB, false);               \
        rA = __builtin_amdgcn_fdot2(u2h(ww[6]), ones, rA, false);               \
        rB = __builtin_amdgcn_fdot2(u2h(ww[7]), ones, rB, false);               \
        l_r += rA + rB;                                                         \
      }                                                                         \
      f16x8 pb0, pb1;                                                           \
      {                                                                         \
        unsigned u0 = ww[0], u1 = ww[1], u2 = ww[2], u3 = ww[3];                \
        swap32(u0, u2); swap32(u1, u3);                                         \
        union { unsigned u[4]; f16x8 v; } c;                                    \
        c.u[0] = u0; c.u[1] = u1; c.u[2] = u2; c.u[3] = u3;                     \
        pb0 = c.v;                                                              \
      }                                                                         \
      {                                                                         \
        unsigned u0 = ww[4], u1 = ww[5], u2 = ww[6], u3 = ww[7];                \
        swap32(u0, u2); swap32(u1, u3);                                         \
        union { unsigned u[4]; f16x8 v; } c;                                    \
        c.u[0] = u0; c.u[1] = u1; c.u[2] = u2; c.u[3] = u3;                     \
        pb1 = c.v;                                                              \
      }                                                                         \
      __builtin_amdgcn_s_setprio(1);                                            \
      _Pragma("unroll")                                                         \
      for (int dn = 0; dn < 2; ++dn) {                                          \
        oacc[dn] = __builtin_amdgcn_mfma_f32_32x32x16_f16(vf[dn * 4 + 0], pb0, oacc[dn], 0, 0, 0); \
        oacc[dn] = __builtin_amdgcn_mfma_f32_32x32x16_f16(vf[dn * 4 + 1], pb1, oacc[dn], 0, 0, 0); \
      }                                                                         \
      __builtin_amdgcn_s_setprio(0);                                            \
    }                                                                           \
    /* ===== half B: keys [32,64) ===== */                                      \
    {                                                                           \
      float v0 = fmaxf(fmaxf(sacc_b[0], sacc_b[1]), sacc_b[2]);                 \
      float v1 = fmaxf(fmaxf(sacc_b[3], sacc_b[4]), sacc_b[5]);                 \
      float v2 = fmaxf(fmaxf(sacc_b[6], sacc_b[7]), sacc_b[8]);                 \
      float v3 = fmaxf(fmaxf(sacc_b[9], sacc_b[10]), sacc_b[11]);               \
      float v4 = fmaxf(fmaxf(sacc_b[12], sacc_b[13]), sacc_b[14]);              \
      float w0 = fmaxf(fmaxf(v0, v1), v2);                                      \
      float w1 = fmaxf(fmaxf(v3, v4), sacc_b[15]);                              \
      float mx = pairmax(fmaxf(w0, w1));                                        \
      if (!__all(mx <= m_r + 8.f)) {                                            \
        float nm = fmaxf(m_r, mx);                                              \
        float sc = fast_exp2(m_r - nm);                                         \
        m_r = nm; l_r *= sc;                                                    \
        _Pragma("unroll")                                                       \
        for (int dn = 0; dn < 2; ++dn)                                          \
          _Pragma("unroll")                                                     \
          for (int r = 0; r < 16; ++r) oacc[dn][r] *= sc;                       \
      }                                                                         \
      unsigned ww[8];                                                           \
      _Pragma("unroll")                                                         \
      for (int r1 = 0; r1 < 4; ++r1) {                                          \
        float p0 = fast_exp2(sacc_b[4 * r1 + 0] - m_r);                         \
        float p1 = fast_exp2(sacc_b[4 * r1 + 1] - m_r);                         \
        float p2 = fast_exp2(sacc_b[4 * r1 + 2] - m_r);                         \
        float p3 = fast_exp2(sacc_b[4 * r1 + 3] - m_r);                         \
        ww[r1 * 2 + 0] = pkrtz(p0, p1);                                         \
        ww[r1 * 2 + 1] = pkrtz(p2, p3);                                         \
      }                                                                         \
      {                                                                         \
        const fp16x2 ones = {(__fp16)1.f, (__fp16)1.f};                         \
        float rA = __builtin_amdgcn_fdot2(u2h(ww[0]), ones, 0.f, false);        \
        float rB = __builtin_amdgcn_fdot2(u2h(ww[1]), ones, 0.f, false);        \
        rA = __builtin_amdgcn_fdot2(u2h(ww[2]), ones, rA, false);               \
        rB = __builtin_amdgcn_fdot2(u2h(ww[3]), ones, rB, false);               \
        rA = __builtin_amdgcn_fdot2(u2h(ww[4]), ones, rA, false);               \
        rB = __builtin_amdgcn_fdot2(u2h(ww[5]), ones, rB, false);               \
        rA = __builtin_amdgcn_fdot2(u2h(ww[6]), ones, rA, false);               \
        rB = __builtin_amdgcn_fdot2(u2h(ww[7]), ones, rB, false);               \
        l_r += rA + rB;                                                         \
      }                                                                         \
      f16x8 pb2, pb3;                                                           \
      {                                                                         \
        unsigned u0 = ww[0], u1 = ww[1], u2 = ww[2], u3 = ww[3];                \
        swap32(u0, u2); swap32(u1, u3);                                         \
        union { unsigned u[4]; f16x8 v; } c;                                    \
        c.u[0] = u0; c.u[1] = u1; c.u[2] = u2; c.u[3] = u3;                     \
        pb2 = c.v;                                                              \
      }                                                                         \
      {                                                                         \
        unsigned u0 = ww[4], u1 = ww[5], u2 = ww[6], u3 = ww[7];                \
        swap32(u0, u2); swap32(u1, u3);                                         \
        union { unsigned u[4]; f16x8 v; } c;                                    \
        c.u[0] = u0; c.u[1] = u1; c.u[2] = u2; c.u[3] = u3;                     \
        pb3 = c.v;                                                              \
      }                                                                         \
      __builtin_amdgcn_s_setprio(1);                                            \
      _Pragma("unroll")                                                         \
      for (int dn = 0; dn < 2; ++dn) {                                          \
        oacc[dn] = __builtin_amdgcn_mfma_f32_32x32x16_f16(vf[dn * 4 + 2], pb2, oacc[dn], 0, 0, 0); \
        oacc[dn] = __builtin_amdgcn_mfma_f32_32x32x16_f16(vf[dn * 4 + 3], pb3, oacc[dn], 0, 0, 0); \
      }                                                                         \
      __builtin_amdgcn_s_setprio(0);                                            \
    }                                                                           \
  }

  for (int it = 0; it < NT; it += 2) {
    TILE_BODY(kbufA, kbufB, it);
    TILE_BODY(kbufB, kbufA, it + 1);
  }
  #undef TILE_BODY

  // ---- epilogue: O^T -> LDS (per-wave 8KB) -> coalesced O stores ----
  const float inv = 1.0f / pairsum(l_r);
  float* Ep = (float*)(smem + wid * 8192);   // [64 d][32 q]
  #pragma unroll
  for (int dn = 0; dn < 2; ++dn)
    #pragma unroll
    for (int r = 0; r < 16; ++r) {
      int d = dn * 32 + (r & 3) + 8 * (r >> 2) + 4 * hi;
      Ep[d * 32 + l31] = oacc[dn][r] * inv;
    }
  __syncthreads();
  const int q2 = lane >> 1, dh = lane & 1;
  float* orow = Ob + (size_t)(qtile * QBLK + wid * 32 + q2) * D_ + dh * 32;
  #pragma unroll
  for (int c = 0; c < 8; ++c) {
    float4 o4;
    o4.x = Ep[(dh * 32 + c * 4 + 0) * 32 + q2];
    o4.y = Ep[(dh * 32 + c * 4 + 1) * 32 + q2];
    o4.z = Ep[(dh * 32 + c * 4 + 2) * 32 + q2];
    o4.w = Ep[(dh * 32 + c * 4 + 3) * 32 + q2];
    *(float4*)(orow + c * 4) = o4;
  }
}

// ---------- fallback (round-3 double-bf16 kernel, used only if ws too small) ----------
__global__ __launch_bounds__(256, 2)
void attn_fwd(const float* __restrict__ Q, const float* __restrict__ K,
              const float* __restrict__ V, float* __restrict__ O) {
  __shared__ alignas(16) unsigned short Kh_lds[KBLK * LDW];
  __shared__ alignas(16) unsigned short Kl_lds[KBLK * LDW];
  __shared__ alignas(16) unsigned short Vt_lds[D_ * LDW];
  __shared__ alignas(16) unsigned short P_lds[4][16 * LDW];

  const int tid  = threadIdx.x;
  const int lane = tid & 63;
  const int wid  = tid >> 6;
  const int l15  = lane & 15;
  const int dgrp = lane >> 4;

  const int qtile = blockIdx.x;
  const int bh    = blockIdx.y;

  const size_t base = (size_t)bh * S_ * D_;
  const float* Qb = Q + base;
  const float* Kb = K + base;
  const float* Vb = V + base;
  float*       Ob = O + base;

  const int qrow = qtile * 64 + wid * 16 + l15;
  short8 qfh[2], qfl[2];
  {
    const float* qp = Qb + (size_t)qrow * D_ + dgrp * 8;
    #pragma unroll
    for (int s = 0; s < 2; ++s)
      #pragma unroll
      for (int j = 0; j < 8; ++j) {
        float f = qp[s * 32 + j];
        unsigned short h = f2bf(f);
        qfh[s][j] = (short)h;
        qfl[s][j] = (short)f2bf(f - bf2f(h));
      }
  }

  f32x4 oacc[4];
  #pragma unroll
  for (int t = 0; t < 4; ++t) oacc[t] = f32x4{0.f, 0.f, 0.f, 0.f};
  float m_r[4], l_r[4];
  #pragma unroll
  for (int j = 0; j < 4; ++j) { m_r[j] = -INFINITY; l_r[j] = 0.f; }

  for (int kb = 0; kb < S_; kb += KBLK) {
    __syncthreads();
    #pragma unroll
    for (int c = 0; c < 4; ++c) {
      int e = (c * 256 + tid) * 4;
      int r = e >> 6, col = e & 63;
      const float4 kv = *(const float4*)(Kb + (size_t)(kb + r) * D_ + col);
      ushort4 kh, kl;
      kh.x = f2bf(kv.x); kl.x = f2bf(kv.x - bf2f(kh.x));
      kh.y = f2bf(kv.y); kl.y = f2bf(kv.y - bf2f(kh.y));
      kh.z = f2bf(kv.z); kl.z = f2bf(kv.z - bf2f(kh.z));
      kh.w = f2bf(kv.w); kl.w = f2bf(kv.w - bf2f(kh.w));
      *(ushort4*)&Kh_lds[r * LDW + col] = kh;
      *(ushort4*)&Kl_lds[r * LDW + col] = kl;
      const float4 vv = *(const float4*)(Vb + (size_t)(kb + r) * D_ + col);
      Vt_lds[(col + 0) * LDW + r] = f2bf(vv.x);
      Vt_lds[(col + 1) * LDW + r] = f2bf(vv.y);
      Vt_lds[(col + 2) * LDW + r] = f2bf(vv.z);
      Vt_lds[(col + 3) * LDW + r] = f2bf(vv.w);
    }
    __syncthreads();

    f32x4 sa[4];
    #pragma unroll
    for (int t = 0; t < 4; ++t) {
      sa[t] = f32x4{0.f, 0.f, 0.f, 0.f};
      #pragma unroll
      for (int s = 0; s < 2; ++s) {
        const int off = (t * 16 + l15) * LDW + s * 32 + dgrp * 8;
        short8 kfh = *(const short8*)&Kh_lds[off];
        short8 kfl = *(const short8*)&Kl_lds[off];
        sa[t] = __builtin_amdgcn_mfma_f32_16x16x32_bf16(qfh[s], kfh, sa[t], 0, 0, 0);
        sa[t] = __builtin_amdgcn_mfma_f32_16x16x32_bf16(qfh[s], kfl, sa[t], 0, 0, 0);
        sa[t] = __builtin_amdgcn_mfma_f32_16x16x32_bf16(qfl[s], kfh, sa[t], 0, 0, 0);
      }
    }

    float pmax[4];
    #pragma unroll
    for (int j = 0; j < 4; ++j) {
      float mx = fmaxf(fmaxf(sa[0][j], sa[1][j]), fmaxf(sa[2][j], sa[3][j]));
      #pragma unroll
      for (int m = 1; m < 16; m <<= 1) mx = fmaxf(mx, __shfl_xor(mx, m));
      pmax[j] = mx;
    }
    float scale[4];
    #pragma unroll
    for (int j = 0; j < 4; ++j) {
      float nm = fmaxf(m_r[j], pmax[j]);
      scale[j] = __expf(m_r[j] - nm);
      m_r[j] = nm;
    }
    float rs[4] = {0.f, 0.f, 0.f, 0.f};
    #pragma unroll
    for (int t = 0; t < 4; ++t)
      #pragma unroll
      for (int j = 0; j < 4; ++j) {
        float p = __expf(sa[t][j] - m_r[j]);
        rs[j] += p;
        P_lds[wid][(dgrp * 4 + j) * LDW + t * 16 + l15] = f2bf(p);
      }
    #pragma unroll
    for (int j = 0; j < 4; ++j) {
      #pragma unroll
      for (int m = 1; m < 16; m <<= 1) rs[j] += __shfl_xor(rs[j], m);
      l_r[j] = l_r[j] * scale[j] + rs[j];
      #pragma unroll
      for (int t = 0; t < 4; ++t) oacc[t][j] *= scale[j];
    }

    #pragma unroll
    for (int s = 0; s < 2; ++s) {
      short8 pf = *(const short8*)&P_lds[wid][l15 * LDW + s * 32 + dgrp * 8];
      #pragma unroll
      for (int t = 0; t < 4; ++t) {
        short8 vf = *(const short8*)&Vt_lds[(t * 16 + l15) * LDW + s * 32 + dgrp * 8];
        oacc[t] = __builtin_amdgcn_mfma_f32_16x16x32_bf16(pf, vf, oacc[t], 0, 0, 0);
      }
    }
  }

  #pragma unroll
  for (int j = 0; j < 4; ++j) {
    float inv = 1.0f / l_r[j];
    int row = qtile * 64 + wid * 16 + dgrp * 4 + j;
    float* op = Ob + (size_t)row * D_ + l15;
    #pragma unroll
    for (int t = 0; t < 4; ++t)
      op[t * 16] = oacc[t][j] * inv;
  }
}

extern "C" void kernel_launch(void* const* d_in, const int* in_sizes, int n_in,
                              void* d_out, int out_size, void* d_ws, size_t ws_size,
                              hipStream_t stream) {
  const float* q = (const float*)d_in[0];
  const float* k = (const float*)d_in[1];
  const float* v = (const float*)d_in[2];
  float* o = (float*)d_out;
  const size_t PLANE = (size_t)B_ * H_ * S_ * 128;   // 16 MiB per fp16 plane
  if (ws_size >= 2 * PLANE) {
    _Float16* Kp = (_Float16*)d_ws;
    _Float16* Vt = (_Float16*)((char*)d_ws + PLANE);
    prep_k<<<8192, 256, 0, stream>>>(k, Kp);
    prep_v<<<2048, 256, 0, stream>>>(v, Vt);
    attn_fwd10<<<dim3(B_ * H_, S_ / QBLK), 256, 0, stream>>>(q, Kp, Vt, o);
  } else {
    attn_fwd<<<dim3(S_ / 64, B_ * H_), 256, 0, stream>>>(q, k, v, o);
  }
}